// Round 9
// baseline (361.746 us; speedup 1.0000x reference)
//
#include <hip/hip_runtime.h>
#include <math.h>

#define SQ   2048
#define DH   64
#define NH   16
#define NB   4
#define QB   128     // q rows per item (8 waves x 16)
#define WVS  8
#define TK   64      // k rows per tile
#define PPD  72      // Psh row stride in shorts

typedef float f32x4  __attribute__((ext_vector_type(4)));
typedef short s16x8  __attribute__((ext_vector_type(8)));
typedef short s16x4  __attribute__((ext_vector_type(4)));

__device__ __forceinline__ short f2bf(float f) {
    union { float f; unsigned u; } x; x.f = f;
    unsigned r = (x.u + 0x7FFFu + ((x.u >> 16) & 1u)) >> 16;  // RNE
    return (short)(unsigned short)r;
}
__device__ __forceinline__ float bf2f(short s) {
    union { unsigned u; float f; } x;
    x.u = ((unsigned)(unsigned short)s) << 16;
    return x.f;
}
__device__ __forceinline__ void gll16(const void* g, void* l) {
    __builtin_amdgcn_global_load_lds(
        (const __attribute__((address_space(1))) unsigned int*)g,
        (__attribute__((address_space(3))) unsigned int*)l, 16, 0, 0);
}

// ---------- merged prepack: kv tiles (blocks 0..2047) + mask bits ----------
__global__ __launch_bounds__(256)
void prepack(const float* __restrict__ Kg, const float* __restrict__ Vg,
             const unsigned int* __restrict__ Mg,
             short* __restrict__ Ktg, short* __restrict__ Vtg,
             unsigned int* __restrict__ mbits)
{
    __shared__ float Vf[64][68];
    const int tid = threadIdx.x;

    if (blockIdx.x < 2048) {          // ---- K/V pack: 64x64 tile, swizzled ----
        const int bh  = blockIdx.x >> 5;
        const int kt  = blockIdx.x & 31;
        const float* ksrc = Kg + ((size_t)bh * SQ + kt * TK) * DH;
        const float* vsrc = Vg + ((size_t)bh * SQ + kt * TK) * DH;
        short* kd = Ktg + (size_t)(bh * 32 + kt) * 4096;
        short* vd = Vtg + (size_t)(bh * 32 + kt) * 4096;

        #pragma unroll
        for (int ii = 0; ii < 4; ++ii) {
            int idx = tid + ii * 256;
            int r = idx >> 4, c0 = (idx & 15) * 4;
            float4 kv = *(const float4*)(ksrc + r * DH + c0);
            s16x4 s; s[0]=f2bf(kv.x); s[1]=f2bf(kv.y); s[2]=f2bf(kv.z); s[3]=f2bf(kv.w);
            int gp = (c0 >> 3) ^ (r & 7);
            *(s16x4*)(kd + r * 64 + gp * 8 + (c0 & 7)) = s;
            float4 vv = *(const float4*)(vsrc + r * DH + c0);
            *(float4*)&Vf[r][c0] = vv;
        }
        __syncthreads();
        #pragma unroll
        for (int ii = 0; ii < 4; ++ii) {
            int idx = tid + ii * 256;
            int d = idx >> 4, k0 = (idx & 15) * 4;
            s16x4 s;
            s[0]=f2bf(Vf[k0+0][d]); s[1]=f2bf(Vf[k0+1][d]);
            s[2]=f2bf(Vf[k0+2][d]); s[3]=f2bf(Vf[k0+3][d]);
            int gp = (k0 >> 3) ^ (d & 7);
            *(s16x4*)(vd + d * 64 + gp * 8 + (k0 & 7)) = s;
        }
    } else {                          // ---- mask pack: 4 rows/block, 1/wave ----
        const int gr   = (blockIdx.x - 2048) * 4 + (tid >> 6);
        const int lane = tid & 63;
        const int b    = gr >> 11;
        const int s    = gr & (SQ - 1);
        bool byteLayout = false;
        #pragma unroll
        for (int i = 0; i < 16; ++i) byteLayout = byteLayout || (Mg[i] > 1u);
        unsigned int* out = mbits + (size_t)b * 64 * SQ + s;
        if (!byteLayout) {
            const unsigned int* rp = Mg + (size_t)gr * SQ;
            #pragma unroll 4
            for (int i = 0; i < 32; ++i) {
                unsigned long long bits = __ballot(rp[i * 64 + lane] != 0u);
                if (lane == 0) {
                    out[(size_t)(2*i)   * SQ] = (unsigned)bits;
                    out[(size_t)(2*i+1) * SQ] = (unsigned)(bits >> 32);
                }
            }
        } else {
            const unsigned char* rp = (const unsigned char*)Mg + (size_t)gr * SQ;
            #pragma unroll 4
            for (int i = 0; i < 32; ++i) {
                unsigned long long bits = __ballot(rp[i * 64 + lane] != 0);
                if (lane == 0) {
                    out[(size_t)(2*i)   * SQ] = (unsigned)bits;
                    out[(size_t)(2*i+1) * SQ] = (unsigned)(bits >> 32);
                }
            }
        }
    }
}

// ------------------------------- hot kernel ---------------------------------
// Each block owns 4 consecutive q-tiles of one bh; 5-phase pipeline:
// L(0) -> [W(0)|L(1)] -> [W(1)|L(2)] -> [W(2)|L(3)] -> W(3).
// Writes flow during ~95% of the kernel; K staged once per kt serves both passes.
__global__ __launch_bounds__(512)
void attn_fused(const float* __restrict__ Qg,
                const short* __restrict__ Ktg, const short* __restrict__ Vtg,
                const unsigned int* __restrict__ mb,
                float* __restrict__ Og, float* __restrict__ Pg)
{
    __shared__ __align__(16) short Ks[2][4096];      // dbuf swizzled K tile
    __shared__ __align__(16) short Vt[2][4096];      // dbuf swizzled V^T tile
    __shared__ __align__(16) short Psh[WVS][16][PPD];// per-wave P tile (bf16)

    const int tid  = threadIdx.x;
    const int lane = tid & 63;
    const int wv   = tid >> 6;        // 0..7
    const int lq   = lane & 15;
    const int lk   = lane >> 4;

    // 256 blocks, bijective XCD chunking: XCD x -> bh [x*8, x*8+8)
    const int g  = (blockIdx.x & 7) * 32 + (blockIdx.x >> 3);
    const int bh = g >> 2;
    const int qg = (g & 3) * 4;       // first of 4 q-tile items
    const int b  = bh >> 4;

    const size_t ktb  = (size_t)bh * 32;
    const int    stgo = wv * 512 + lane * 8;
    const int swz0 = (lk ^ (lq & 7)) << 3;
    const int swz1 = ((4 + lk) ^ (lq & 7)) << 3;

    auto loadQ = [&](int item, s16x8* qf) {
        const float* qrow = Qg + ((size_t)bh * SQ + (qg + item) * QB + wv * 16 + lq) * DH;
        #pragma unroll
        for (int c = 0; c < 2; ++c) {
            const float4* p = (const float4*)(qrow + c * 32 + lk * 8);
            float4 a = p[0], bb = p[1];
            qf[c][0]=f2bf(0.125f*a.x);  qf[c][1]=f2bf(0.125f*a.y);
            qf[c][2]=f2bf(0.125f*a.z);  qf[c][3]=f2bf(0.125f*a.w);
            qf[c][4]=f2bf(0.125f*bb.x); qf[c][5]=f2bf(0.125f*bb.y);
            qf[c][6]=f2bf(0.125f*bb.z); qf[c][7]=f2bf(0.125f*bb.w);
        }
    };
    auto mbaseOf = [&](int item) -> size_t {
        return (size_t)b * 64 * SQ + (qg + item) * QB + wv * 16
             + ((size_t)((lane >> 4) & 1)) * SQ + (lane & 15);
    };

    s16x8 qfW[2], qfL[2];
    float l[4], linv[4];
    f32x4 oa[4];

    // =================== phase 0: L-only, item 0 ===================
    loadQ(0, qfL);
    #pragma unroll
    for (int r = 0; r < 4; ++r) l[r] = 0.f;
    {
        const size_t mbL = mbaseOf(0);
        gll16(Ktg + ktb * 4096 + stgo, &Ks[0][stgo]);
        __syncthreads();
        #pragma unroll 1
        for (int kt = 0; kt < SQ / TK; ++kt) {
            const int cb = kt & 1;
            if (kt + 1 < SQ / TK)
                gll16(Ktg + (ktb + kt + 1) * 4096 + stgo, &Ks[cb ^ 1][stgo]);
            const unsigned mw = mb[mbL + (size_t)(kt * 2) * SQ];
            f32x4 acc[4];
            #pragma unroll
            for (int nt = 0; nt < 4; ++nt) {
                acc[nt] = (f32x4){0.f, 0.f, 0.f, 0.f};
                const int R = nt * 16 + lq;
                s16x8 kf0 = *(const s16x8*)(&Ks[cb][R * 64] + swz0);
                s16x8 kf1 = *(const s16x8*)(&Ks[cb][R * 64] + swz1);
                acc[nt] = __builtin_amdgcn_mfma_f32_16x16x32_bf16(qfL[0], kf0, acc[nt], 0, 0, 0);
                acc[nt] = __builtin_amdgcn_mfma_f32_16x16x32_bf16(qfL[1], kf1, acc[nt], 0, 0, 0);
            }
            #pragma unroll
            for (int r = 0; r < 4; ++r) {
                const unsigned bits0 = __shfl(mw, lk * 4 + r, 64);
                const unsigned bits1 = __shfl(mw, 16 + lk * 4 + r, 64);
                float s = 0.f;
                #pragma unroll
                for (int nt = 0; nt < 4; ++nt) {
                    float x = acc[nt][r];
                    unsigned bits = (nt < 2) ? bits0 : bits1;
                    if ((bits >> ((nt * 16 + lq) & 31)) & 1u) x = -1e30f;
                    s += __expf(x);
                }
                l[r] += s;
            }
            __syncthreads();
        }
    }
    #pragma unroll
    for (int r = 0; r < 4; ++r) {
        #pragma unroll
        for (int x = 1; x < 16; x <<= 1) l[r] += __shfl_xor(l[r], x, 64);
        linv[r] = 1.0f / l[r];
    }
    qfW[0] = qfL[0]; qfW[1] = qfL[1];

    // ============== phases 1..4: W(ph-1) [+ L(ph) while ph<=3] ==============
    #pragma unroll 1
    for (int ph = 1; ph <= 4; ++ph) {
        const int  itW  = ph - 1;
        const bool hasL = (ph <= 3);
        if (hasL) {
            loadQ(ph, qfL);
            #pragma unroll
            for (int r = 0; r < 4; ++r) l[r] = 0.f;
        }
        const size_t mbW = mbaseOf(itW);
        const size_t mbL = hasL ? mbaseOf(ph) : mbW;
        float* Pdir = Pg + (size_t)bh * SQ * SQ
                    + (size_t)((qg + itW) * QB + wv * 16) * SQ;
        #pragma unroll
        for (int dt = 0; dt < 4; ++dt) oa[dt] = (f32x4){0.f, 0.f, 0.f, 0.f};

        gll16(Ktg + ktb * 4096 + stgo, &Ks[0][stgo]);
        gll16(Vtg + ktb * 4096 + stgo, &Vt[0][stgo]);
        __syncthreads();

        #pragma unroll 1
        for (int kt = 0; kt < SQ / TK; ++kt) {
            const int cb = kt & 1;
            if (kt + 1 < SQ / TK) {
                gll16(Ktg + (ktb + kt + 1) * 4096 + stgo, &Ks[cb ^ 1][stgo]);
                gll16(Vtg + (ktb + kt + 1) * 4096 + stgo, &Vt[cb ^ 1][stgo]);
            }
            // ---------- W path: QK^T -> P -> nt store + PV ----------
            {
                const unsigned mwW = mb[mbW + (size_t)(kt * 2) * SQ];
                unsigned w0[4], w1[4];
                #pragma unroll
                for (int r = 0; r < 4; ++r) {
                    w0[r] = __shfl(mwW, lk * 4 + r, 64);
                    w1[r] = __shfl(mwW, 16 + lk * 4 + r, 64);
                }
                #pragma unroll
                for (int nt = 0; nt < 4; ++nt) {
                    f32x4 acc = {0.f, 0.f, 0.f, 0.f};
                    const int R = nt * 16 + lq;
                    s16x8 kf0 = *(const s16x8*)(&Ks[cb][R * 64] + swz0);
                    s16x8 kf1 = *(const s16x8*)(&Ks[cb][R * 64] + swz1);
                    acc = __builtin_amdgcn_mfma_f32_16x16x32_bf16(qfW[0], kf0, acc, 0, 0, 0);
                    acc = __builtin_amdgcn_mfma_f32_16x16x32_bf16(qfW[1], kf1, acc, 0, 0, 0);
                    #pragma unroll
                    for (int r = 0; r < 4; ++r) {
                        float x = acc[r];
                        unsigned bits = (nt < 2) ? w0[r] : w1[r];
                        if ((bits >> ((nt * 16 + lq) & 31)) & 1u) x = -1e30f;
                        Psh[wv][lk * 4 + r][nt * 16 + lq] = f2bf(__expf(x) * linv[r]);
                    }
                }
                asm volatile("s_waitcnt lgkmcnt(0)" ::: "memory");
                __builtin_amdgcn_sched_barrier(0);
                #pragma unroll
                for (int i = 0; i < 4; ++i) {
                    int f = lane + i * 64;
                    int row = f >> 4, c4 = f & 15;
                    s16x4 pb = *(const s16x4*)&Psh[wv][row][c4 * 4];
                    f32x4 pv;
                    pv[0]=bf2f(pb[0]); pv[1]=bf2f(pb[1]);
                    pv[2]=bf2f(pb[2]); pv[3]=bf2f(pb[3]);
                    __builtin_nontemporal_store(
                        pv, (f32x4*)(Pdir + (size_t)row * SQ + kt * TK + c4 * 4));
                }
                #pragma unroll
                for (int c = 0; c < 2; ++c) {
                    s16x8 pa = *(const s16x8*)&Psh[wv][lq][c * 32 + lk * 8];
                    #pragma unroll
                    for (int dt = 0; dt < 4; ++dt) {
                        const int Rv = dt * 16 + lq;
                        const int swzv = (((4 * c + lk) ^ (lq & 7)) << 3);
                        s16x8 vb = *(const s16x8*)(&Vt[cb][Rv * 64] + swzv);
                        oa[dt] = __builtin_amdgcn_mfma_f32_16x16x32_bf16(pa, vb, oa[dt], 0, 0, 0);
                    }
                }
            }
            // ---------- L path (next item's denominator) ----------
            if (hasL) {
                const unsigned mwL = mb[mbL + (size_t)(kt * 2) * SQ];
                f32x4 accl[4];
                #pragma unroll
                for (int nt = 0; nt < 4; ++nt) {
                    accl[nt] = (f32x4){0.f, 0.f, 0.f, 0.f};
                    const int R = nt * 16 + lq;
                    s16x8 kf0 = *(const s16x8*)(&Ks[cb][R * 64] + swz0);
                    s16x8 kf1 = *(const s16x8*)(&Ks[cb][R * 64] + swz1);
                    accl[nt] = __builtin_amdgcn_mfma_f32_16x16x32_bf16(qfL[0], kf0, accl[nt], 0, 0, 0);
                    accl[nt] = __builtin_amdgcn_mfma_f32_16x16x32_bf16(qfL[1], kf1, accl[nt], 0, 0, 0);
                }
                #pragma unroll
                for (int r = 0; r < 4; ++r) {
                    const unsigned bits0 = __shfl(mwL, lk * 4 + r, 64);
                    const unsigned bits1 = __shfl(mwL, 16 + lk * 4 + r, 64);
                    float s = 0.f;
                    #pragma unroll
                    for (int nt = 0; nt < 4; ++nt) {
                        float x = accl[nt][r];
                        unsigned bits = (nt < 2) ? bits0 : bits1;
                        if ((bits >> ((nt * 16 + lq) & 31)) & 1u) x = -1e30f;
                        s += __expf(x);
                    }
                    l[r] += s;
                }
            }
            __syncthreads();
        }
        // O write for itW
        {
            float* orow = Og + ((size_t)bh * SQ + (qg + itW) * QB + wv * 16) * DH;
            #pragma unroll
            for (int dt = 0; dt < 4; ++dt)
                #pragma unroll
                for (int r = 0; r < 4; ++r)
                    __builtin_nontemporal_store(
                        oa[dt][r], &orow[(size_t)(lk * 4 + r) * DH + dt * 16 + lq]);
        }
        if (hasL) {
            #pragma unroll
            for (int r = 0; r < 4; ++r) {
                #pragma unroll
                for (int x = 1; x < 16; x <<= 1) l[r] += __shfl_xor(l[r], x, 64);
                linv[r] = 1.0f / l[r];
            }
            qfW[0] = qfL[0]; qfW[1] = qfL[1];
        }
    }
}

extern "C" void kernel_launch(void* const* d_in, const int* in_sizes, int n_in,
                              void* d_out, int out_size, void* d_ws, size_t ws_size,
                              hipStream_t stream) {
    const float*        Q = (const float*)d_in[0];
    const float*        K = (const float*)d_in[1];
    const float*        V = (const float*)d_in[2];
    const unsigned int* M = (const unsigned int*)d_in[3];

    float* out  = (float*)d_out;
    float* outO = out;                                    // [B,H,S,D]
    float* outP = out + (size_t)NB * NH * SQ * DH;        // [B,H,S,S]

    // workspace: mask bits (2 MB) | K tiled bf16 (16.8 MB) | V tiled (16.8 MB)
    unsigned int* mbits = (unsigned int*)d_ws;
    short* Ktg = (short*)(mbits + (size_t)NB * SQ * 64);
    short* Vtg = Ktg + (size_t)NB * NH * SQ * DH;

    hipLaunchKernelGGL(prepack, dim3(4096), dim3(256), 0, stream,
                       K, V, M, Ktg, Vtg, mbits);
    hipLaunchKernelGGL(attn_fused, dim3(256), dim3(512), 0, stream,
                       Q, Ktg, Vtg, mbits, outO, outP);
}

// Round 10
// 283.563 us; speedup vs baseline: 1.2757x; 1.2757x over previous
//
#include <hip/hip_runtime.h>
#include <math.h>

#define SQ   2048
#define DH   64
#define NH   16
#define NB   4
#define QB   128     // q rows per item (8 waves x 16)
#define WVS  8
#define TK   64      // k rows per tile
#define PPD  72      // Psh row stride in shorts

typedef float f32x4  __attribute__((ext_vector_type(4)));
typedef short s16x8  __attribute__((ext_vector_type(8)));
typedef short s16x4  __attribute__((ext_vector_type(4)));

__device__ __forceinline__ short f2bf(float f) {
    union { float f; unsigned u; } x; x.f = f;
    unsigned r = (x.u + 0x7FFFu + ((x.u >> 16) & 1u)) >> 16;  // RNE
    return (short)(unsigned short)r;
}
__device__ __forceinline__ float bf2f(short s) {
    union { unsigned u; float f; } x;
    x.u = ((unsigned)(unsigned short)s) << 16;
    return x.f;
}
__device__ __forceinline__ void gll16(const void* g, void* l) {
    __builtin_amdgcn_global_load_lds(
        (const __attribute__((address_space(1))) unsigned int*)g,
        (__attribute__((address_space(3))) unsigned int*)l, 16, 0, 0);
}

// ---------- merged prepack: kv tiles (blocks 0..2047) + mask bits ----------
__global__ __launch_bounds__(256)
void prepack(const float* __restrict__ Kg, const float* __restrict__ Vg,
             const unsigned int* __restrict__ Mg,
             short* __restrict__ Ktg, short* __restrict__ Vtg,
             unsigned int* __restrict__ mbits)
{
    __shared__ float Vf[64][68];
    const int tid = threadIdx.x;

    if (blockIdx.x < 2048) {          // ---- K/V pack: 64x64 tile, swizzled ----
        const int bh  = blockIdx.x >> 5;
        const int kt  = blockIdx.x & 31;
        const float* ksrc = Kg + ((size_t)bh * SQ + kt * TK) * DH;
        const float* vsrc = Vg + ((size_t)bh * SQ + kt * TK) * DH;
        short* kd = Ktg + (size_t)(bh * 32 + kt) * 4096;
        short* vd = Vtg + (size_t)(bh * 32 + kt) * 4096;

        #pragma unroll
        for (int ii = 0; ii < 4; ++ii) {
            int idx = tid + ii * 256;
            int r = idx >> 4, c0 = (idx & 15) * 4;
            float4 kv = *(const float4*)(ksrc + r * DH + c0);
            s16x4 s; s[0]=f2bf(kv.x); s[1]=f2bf(kv.y); s[2]=f2bf(kv.z); s[3]=f2bf(kv.w);
            int gp = (c0 >> 3) ^ (r & 7);
            *(s16x4*)(kd + r * 64 + gp * 8 + (c0 & 7)) = s;
            float4 vv = *(const float4*)(vsrc + r * DH + c0);
            *(float4*)&Vf[r][c0] = vv;
        }
        __syncthreads();
        #pragma unroll
        for (int ii = 0; ii < 4; ++ii) {
            int idx = tid + ii * 256;
            int d = idx >> 4, k0 = (idx & 15) * 4;
            s16x4 s;
            s[0]=f2bf(Vf[k0+0][d]); s[1]=f2bf(Vf[k0+1][d]);
            s[2]=f2bf(Vf[k0+2][d]); s[3]=f2bf(Vf[k0+3][d]);
            int gp = (k0 >> 3) ^ (d & 7);
            *(s16x4*)(vd + d * 64 + gp * 8 + (k0 & 7)) = s;
        }
    } else {                          // ---- mask pack: 4 rows/block, 1/wave ----
        const int gr   = (blockIdx.x - 2048) * 4 + (tid >> 6);
        const int lane = tid & 63;
        const int b    = gr >> 11;
        const int s    = gr & (SQ - 1);
        bool byteLayout = false;
        #pragma unroll
        for (int i = 0; i < 16; ++i) byteLayout = byteLayout || (Mg[i] > 1u);
        unsigned int* out = mbits + (size_t)b * 64 * SQ + s;
        if (!byteLayout) {
            const unsigned int* rp = Mg + (size_t)gr * SQ;
            #pragma unroll 4
            for (int i = 0; i < 32; ++i) {
                unsigned long long bits = __ballot(rp[i * 64 + lane] != 0u);
                if (lane == 0) {
                    out[(size_t)(2*i)   * SQ] = (unsigned)bits;
                    out[(size_t)(2*i+1) * SQ] = (unsigned)(bits >> 32);
                }
            }
        } else {
            const unsigned char* rp = (const unsigned char*)Mg + (size_t)gr * SQ;
            #pragma unroll 4
            for (int i = 0; i < 32; ++i) {
                unsigned long long bits = __ballot(rp[i * 64 + lane] != 0);
                if (lane == 0) {
                    out[(size_t)(2*i)   * SQ] = (unsigned)bits;
                    out[(size_t)(2*i+1) * SQ] = (unsigned)(bits >> 32);
                }
            }
        }
    }
}

// ------------------------------- hot kernel ---------------------------------
// Depth-2 pipeline, occupancy-preserving: each block owns 2 q-tiles;
// phases L(0) -> [W(0)|L(1)] -> W(1). __launch_bounds__(512,4) caps VGPR
// at 128 so 2 blocks/CU (16 waves) co-reside.
__global__ __launch_bounds__(512, 4)
void attn_fused(const float* __restrict__ Qg,
                const short* __restrict__ Ktg, const short* __restrict__ Vtg,
                const unsigned int* __restrict__ mb,
                float* __restrict__ Og, float* __restrict__ Pg)
{
    __shared__ __align__(16) short Ks[2][4096];      // dbuf swizzled K tile
    __shared__ __align__(16) short Vt[2][4096];      // dbuf swizzled V^T tile
    __shared__ __align__(16) short Psh[WVS][16][PPD];// per-wave P tile (bf16)

    const int tid  = threadIdx.x;
    const int lane = tid & 63;
    const int wv   = tid >> 6;        // 0..7
    const int lq   = lane & 15;
    const int lk   = lane >> 4;

    // 512 blocks, bijective XCD chunking: XCD x -> 64 consecutive pair-items
    const int g    = (blockIdx.x & 7) * 64 + (blockIdx.x >> 3);
    const int bh   = g >> 3;          // 0..63
    const int pair = g & 7;           // 2 q-tiles: 2*pair, 2*pair+1
    const int b    = bh >> 4;

    const size_t ktb  = (size_t)bh * 32;
    const int    stgo = wv * 512 + lane * 8;
    const int swz0 = (lk ^ (lq & 7)) << 3;
    const int swz1 = ((4 + lk) ^ (lq & 7)) << 3;

    auto loadQ = [&](int item, s16x8* qf) {
        const float* qrow = Qg + ((size_t)bh * SQ + (pair * 2 + item) * QB + wv * 16 + lq) * DH;
        #pragma unroll
        for (int c = 0; c < 2; ++c) {
            const float4* p = (const float4*)(qrow + c * 32 + lk * 8);
            float4 a = p[0], bb = p[1];
            qf[c][0]=f2bf(0.125f*a.x);  qf[c][1]=f2bf(0.125f*a.y);
            qf[c][2]=f2bf(0.125f*a.z);  qf[c][3]=f2bf(0.125f*a.w);
            qf[c][4]=f2bf(0.125f*bb.x); qf[c][5]=f2bf(0.125f*bb.y);
            qf[c][6]=f2bf(0.125f*bb.z); qf[c][7]=f2bf(0.125f*bb.w);
        }
    };
    auto mbaseOf = [&](int item) -> size_t {
        return (size_t)b * 64 * SQ + (pair * 2 + item) * QB + wv * 16
             + ((size_t)((lane >> 4) & 1)) * SQ + (lane & 15);
    };

    s16x8 qfW[2], qfL[2];
    float l[4], linv[4];
    f32x4 oa[4];

    // =================== phase 0: L-only, item 0 ===================
    loadQ(0, qfL);
    #pragma unroll
    for (int r = 0; r < 4; ++r) l[r] = 0.f;
    {
        const size_t mbL = mbaseOf(0);
        gll16(Ktg + ktb * 4096 + stgo, &Ks[0][stgo]);
        __syncthreads();
        #pragma unroll 1
        for (int kt = 0; kt < SQ / TK; ++kt) {
            const int cb = kt & 1;
            if (kt + 1 < SQ / TK)
                gll16(Ktg + (ktb + kt + 1) * 4096 + stgo, &Ks[cb ^ 1][stgo]);
            const unsigned mw = mb[mbL + (size_t)(kt * 2) * SQ];
            f32x4 acc[4];
            #pragma unroll
            for (int nt = 0; nt < 4; ++nt) {
                acc[nt] = (f32x4){0.f, 0.f, 0.f, 0.f};
                const int R = nt * 16 + lq;
                s16x8 kf0 = *(const s16x8*)(&Ks[cb][R * 64] + swz0);
                s16x8 kf1 = *(const s16x8*)(&Ks[cb][R * 64] + swz1);
                acc[nt] = __builtin_amdgcn_mfma_f32_16x16x32_bf16(qfL[0], kf0, acc[nt], 0, 0, 0);
                acc[nt] = __builtin_amdgcn_mfma_f32_16x16x32_bf16(qfL[1], kf1, acc[nt], 0, 0, 0);
            }
            #pragma unroll
            for (int r = 0; r < 4; ++r) {
                const unsigned bits0 = __shfl(mw, lk * 4 + r, 64);
                const unsigned bits1 = __shfl(mw, 16 + lk * 4 + r, 64);
                float s = 0.f;
                #pragma unroll
                for (int nt = 0; nt < 4; ++nt) {
                    float x = acc[nt][r];
                    unsigned bits = (nt < 2) ? bits0 : bits1;
                    if ((bits >> ((nt * 16 + lq) & 31)) & 1u) x = -1e30f;
                    s += __expf(x);
                }
                l[r] += s;
            }
            __syncthreads();
        }
    }
    #pragma unroll
    for (int r = 0; r < 4; ++r) {
        #pragma unroll
        for (int x = 1; x < 16; x <<= 1) l[r] += __shfl_xor(l[r], x, 64);
        linv[r] = 1.0f / l[r];
    }
    qfW[0] = qfL[0]; qfW[1] = qfL[1];

    // ============== phases 1..2: W(ph-1) [+ L(1) in phase 1] ==============
    #pragma unroll 1
    for (int ph = 1; ph <= 2; ++ph) {
        const int  itW  = ph - 1;
        const bool hasL = (ph == 1);
        if (hasL) {
            loadQ(1, qfL);
            #pragma unroll
            for (int r = 0; r < 4; ++r) l[r] = 0.f;
        }
        const size_t mbW = mbaseOf(itW);
        const size_t mbL = hasL ? mbaseOf(1) : mbW;
        float* Pdir = Pg + (size_t)bh * SQ * SQ
                    + (size_t)((pair * 2 + itW) * QB + wv * 16) * SQ;
        #pragma unroll
        for (int dt = 0; dt < 4; ++dt) oa[dt] = (f32x4){0.f, 0.f, 0.f, 0.f};

        gll16(Ktg + ktb * 4096 + stgo, &Ks[0][stgo]);
        gll16(Vtg + ktb * 4096 + stgo, &Vt[0][stgo]);
        __syncthreads();

        #pragma unroll 1
        for (int kt = 0; kt < SQ / TK; ++kt) {
            const int cb = kt & 1;
            if (kt + 1 < SQ / TK) {
                gll16(Ktg + (ktb + kt + 1) * 4096 + stgo, &Ks[cb ^ 1][stgo]);
                gll16(Vtg + (ktb + kt + 1) * 4096 + stgo, &Vt[cb ^ 1][stgo]);
            }
            // ---------- W path: QK^T -> P -> nt store + PV ----------
            {
                const unsigned mwW = mb[mbW + (size_t)(kt * 2) * SQ];
                unsigned w0[4], w1[4];
                #pragma unroll
                for (int r = 0; r < 4; ++r) {
                    w0[r] = __shfl(mwW, lk * 4 + r, 64);
                    w1[r] = __shfl(mwW, 16 + lk * 4 + r, 64);
                }
                #pragma unroll
                for (int nt = 0; nt < 4; ++nt) {
                    f32x4 acc = {0.f, 0.f, 0.f, 0.f};
                    const int R = nt * 16 + lq;
                    s16x8 kf0 = *(const s16x8*)(&Ks[cb][R * 64] + swz0);
                    s16x8 kf1 = *(const s16x8*)(&Ks[cb][R * 64] + swz1);
                    acc = __builtin_amdgcn_mfma_f32_16x16x32_bf16(qfW[0], kf0, acc, 0, 0, 0);
                    acc = __builtin_amdgcn_mfma_f32_16x16x32_bf16(qfW[1], kf1, acc, 0, 0, 0);
                    #pragma unroll
                    for (int r = 0; r < 4; ++r) {
                        float x = acc[r];
                        unsigned bits = (nt < 2) ? w0[r] : w1[r];
                        if ((bits >> ((nt * 16 + lq) & 31)) & 1u) x = -1e30f;
                        Psh[wv][lk * 4 + r][nt * 16 + lq] = f2bf(__expf(x) * linv[r]);
                    }
                }
                asm volatile("s_waitcnt lgkmcnt(0)" ::: "memory");
                __builtin_amdgcn_sched_barrier(0);
                #pragma unroll
                for (int i = 0; i < 4; ++i) {
                    int f = lane + i * 64;
                    int row = f >> 4, c4 = f & 15;
                    s16x4 pb = *(const s16x4*)&Psh[wv][row][c4 * 4];
                    f32x4 pv;
                    pv[0]=bf2f(pb[0]); pv[1]=bf2f(pb[1]);
                    pv[2]=bf2f(pb[2]); pv[3]=bf2f(pb[3]);
                    __builtin_nontemporal_store(
                        pv, (f32x4*)(Pdir + (size_t)row * SQ + kt * TK + c4 * 4));
                }
                #pragma unroll
                for (int c = 0; c < 2; ++c) {
                    s16x8 pa = *(const s16x8*)&Psh[wv][lq][c * 32 + lk * 8];
                    #pragma unroll
                    for (int dt = 0; dt < 4; ++dt) {
                        const int Rv = dt * 16 + lq;
                        const int swzv = (((4 * c + lk) ^ (lq & 7)) << 3);
                        s16x8 vb = *(const s16x8*)(&Vt[cb][Rv * 64] + swzv);
                        oa[dt] = __builtin_amdgcn_mfma_f32_16x16x32_bf16(pa, vb, oa[dt], 0, 0, 0);
                    }
                }
            }
            // ---------- L path (item 1's denominator) ----------
            if (hasL) {
                const unsigned mwL = mb[mbL + (size_t)(kt * 2) * SQ];
                f32x4 accl[4];
                #pragma unroll
                for (int nt = 0; nt < 4; ++nt) {
                    accl[nt] = (f32x4){0.f, 0.f, 0.f, 0.f};
                    const int R = nt * 16 + lq;
                    s16x8 kf0 = *(const s16x8*)(&Ks[cb][R * 64] + swz0);
                    s16x8 kf1 = *(const s16x8*)(&Ks[cb][R * 64] + swz1);
                    accl[nt] = __builtin_amdgcn_mfma_f32_16x16x32_bf16(qfL[0], kf0, accl[nt], 0, 0, 0);
                    accl[nt] = __builtin_amdgcn_mfma_f32_16x16x32_bf16(qfL[1], kf1, accl[nt], 0, 0, 0);
                }
                #pragma unroll
                for (int r = 0; r < 4; ++r) {
                    const unsigned bits0 = __shfl(mwL, lk * 4 + r, 64);
                    const unsigned bits1 = __shfl(mwL, 16 + lk * 4 + r, 64);
                    float s = 0.f;
                    #pragma unroll
                    for (int nt = 0; nt < 4; ++nt) {
                        float x = accl[nt][r];
                        unsigned bits = (nt < 2) ? bits0 : bits1;
                        if ((bits >> ((nt * 16 + lq) & 31)) & 1u) x = -1e30f;
                        s += __expf(x);
                    }
                    l[r] += s;
                }
            }
            __syncthreads();
        }
        // O write for itW
        {
            float* orow = Og + ((size_t)bh * SQ + (pair * 2 + itW) * QB + wv * 16) * DH;
            #pragma unroll
            for (int dt = 0; dt < 4; ++dt)
                #pragma unroll
                for (int r = 0; r < 4; ++r)
                    __builtin_nontemporal_store(
                        oa[dt][r], &orow[(size_t)(lk * 4 + r) * DH + dt * 16 + lq]);
        }
        if (hasL) {
            #pragma unroll
            for (int r = 0; r < 4; ++r) {
                #pragma unroll
                for (int x = 1; x < 16; x <<= 1) l[r] += __shfl_xor(l[r], x, 64);
                linv[r] = 1.0f / l[r];
            }
            qfW[0] = qfL[0]; qfW[1] = qfL[1];
        }
    }
}

extern "C" void kernel_launch(void* const* d_in, const int* in_sizes, int n_in,
                              void* d_out, int out_size, void* d_ws, size_t ws_size,
                              hipStream_t stream) {
    const float*        Q = (const float*)d_in[0];
    const float*        K = (const float*)d_in[1];
    const float*        V = (const float*)d_in[2];
    const unsigned int* M = (const unsigned int*)d_in[3];

    float* out  = (float*)d_out;
    float* outO = out;                                    // [B,H,S,D]
    float* outP = out + (size_t)NB * NH * SQ * DH;        // [B,H,S,S]

    // workspace: mask bits (2 MB) | K tiled bf16 (16.8 MB) | V tiled (16.8 MB)
    unsigned int* mbits = (unsigned int*)d_ws;
    short* Ktg = (short*)(mbits + (size_t)NB * SQ * 64);
    short* Vtg = Ktg + (size_t)NB * NH * SQ * DH;

    hipLaunchKernelGGL(prepack, dim3(4096), dim3(256), 0, stream,
                       K, V, M, Ktg, Vtg, mbits);
    hipLaunchKernelGGL(attn_fused, dim3(512), dim3(512), 0, stream,
                       Q, Ktg, Vtg, mbits, outO, outP);
}